// Round 10
// baseline (620.350 us; speedup 1.0000x reference)
//
#include <hip/hip_runtime.h>
#include <math.h>

#define DDIM 16
#define NSTEPS 64

typedef __fp16   fp16x2  __attribute__((ext_vector_type(2)));
typedef _Float16 h2      __attribute__((ext_vector_type(2)));
typedef _Float16 half4   __attribute__((ext_vector_type(4)));
typedef float    floatx4 __attribute__((ext_vector_type(4)));

union pk_u      { fp16x2 fv; h2 hv; unsigned u; };
union h2x2_h4   { h2 g2[2]; half4 h4; };
union pk2_to_h4 { fp16x2 p2[2]; half4 h4; };

// ---------------------------------------------------------------------------
// Pre-pack W^T / V^T into per-lane MFMA A-operand fragments (f16).
// V fragments are pre-scaled by 1/NSTEPS.
// ---------------------------------------------------------------------------
__global__ __launch_bounds__(256) void pack_wv(const float* __restrict__ W,
                                               const float* __restrict__ V,
                                               half4* __restrict__ pw,
                                               half4* __restrict__ pv)
{
    int t = blockIdx.x * 256 + threadIdx.x;   // 0..4095 = 64 steps * 64 lanes
    int L = t & 63;
    int s = t >> 6;
    int q = L >> 4, r = L & 15;
    const float inv_n = 1.0f / (float)NSTEPS;
    const float* Ws = W + s * DDIM * DDIM;
    const float* Vs = V + s * DDIM * DDIM;
    half4 w, v;
    #pragma unroll
    for (int j = 0; j < 4; ++j) {
        w[j] = (_Float16)Ws[(4 * q + j) * DDIM + r];
        v[j] = (_Float16)(Vs[(4 * q + j) * DDIM + r] * inv_n);
    }
    pw[t] = w;
    pv[t] = v;
}

// ---------------------------------------------------------------------------
// Main kernel — LDS-FREE GELU.
//   gelu(x) = relu(x) + delta(|x|),  delta = gelu - relu is EVEN, smooth,
//   in [-0.17, 0], decaying to 0.  delta approximated by a deg-7 polynomial
//   in z = min(|x|,3.2) - 1.6 (centered so f16 coefficient quantization is
//   negligible; Horner intermediates <= 0.18 so f16 eval noise ~1e-3).
//   Fit: divided differences on exact normal-CDF values, nodes
//   t = {0,.25,.75,1.25,1.75,2.25,2.75,3.2}; off-node err <= ~1.3e-4;
//   tail (|x|>3.2, poly held at -0.0033) err <= 3.3e-3.
// Per element pair: 12 packed-f16 ops (and,min,sub, 7 fma, max, add).
// No LDS, no __syncthreads, no bank conflicts — removes the 4 gathers/tile
// whose ~5.8cy pipe cost + ~120cy latency was the invariant R4-R8 floor.
// ---------------------------------------------------------------------------
__global__ __launch_bounds__(256) void resnet_mfma_kernel(
    const float* __restrict__ x,
    const half4* __restrict__ pw,
    const half4* __restrict__ pv,
    float* __restrict__ out)
{
    const int tid  = threadIdx.x;
    const int lane = tid & 63;
    const int wave = tid >> 6;
    const int q = lane >> 4, r = lane & 15;

    const long rowbase = (long)blockIdx.x * 256 + (long)wave * 64;

    floatx4 h[4];
    #pragma unroll
    for (int t = 0; t < 4; ++t) {
        const float4* p = reinterpret_cast<const float4*>(
            x + (rowbase + t * 16 + r) * DDIM + 4 * q);
        float4 v = *p;
        h[t][0] = v.x; h[t][1] = v.y; h[t][2] = v.z; h[t][3] = v.w;
    }

    // delta(z) coefficients, z = t - 1.6 (power basis, f16-friendly)
    #define H2C(c) h2{(_Float16)(c), (_Float16)(c)}
    const h2 C7 = H2C( 0.0007539f);
    const h2 C6 = H2C(-0.00309872f);
    const h2 C5 = H2C(-0.00384931f);
    const h2 C4 = H2C( 0.03301614f);
    const h2 C3 = H2C(-0.04345638f);
    const h2 C2 = H2C(-0.03059348f);
    const h2 C1 = H2C( 0.12280222f);
    const h2 C0 = H2C(-0.08770670f);
    const h2 TCLAMP = H2C(3.19921875f);   // f16-exact 3.2
    const h2 TSHIFT = H2C(1.59960938f);   // f16-exact 1.6
    const h2 HZERO  = H2C(0.0f);
    #undef H2C

    half4 wf = pw[lane];
    half4 vf = pv[lane];

    for (int s = 0; s < NSTEPS; ++s) {
        int sn = (s + 1) & (NSTEPS - 1);          // last iter wraps to 0 (unused)
        half4 wfn = pw[sn * 64 + lane];
        half4 vfn = pv[sn * 64 + lane];

        #pragma unroll
        for (int t = 0; t < 4; ++t) {
            pk2_to_h4 hc;
            hc.p2[0] = __builtin_amdgcn_cvt_pkrtz(h[t][0], h[t][1]);
            hc.p2[1] = __builtin_amdgcn_cvt_pkrtz(h[t][2], h[t][3]);

            floatx4 zero = {0.f, 0.f, 0.f, 0.f};
            floatx4 u = __builtin_amdgcn_mfma_f32_16x16x16f16(wf, hc.h4, zero, 0, 0, 0);

            // u -> packed f16 pairs (poly input AND relu operand)
            pk_u P01, P23;
            P01.fv = __builtin_amdgcn_cvt_pkrtz(u[0], u[1]);
            P23.fv = __builtin_amdgcn_cvt_pkrtz(u[2], u[3]);

            h2x2_h4 gg;
            #pragma unroll
            for (int pr = 0; pr < 2; ++pr) {
                pk_u U = (pr == 0) ? P01 : P23;
                pk_u T; T.u = U.u & 0x7FFF7FFFu;                    // |u| packed
                h2 tc = __builtin_elementwise_min(T.hv, TCLAMP);
                h2 z  = tc - TSHIFT;                                // v_pk_add
                h2 acc = C7;
                acc = acc * z + C6;                                 // v_pk_fma_f16
                acc = acc * z + C5;
                acc = acc * z + C4;
                acc = acc * z + C3;
                acc = acc * z + C2;
                acc = acc * z + C1;
                h2 delta = acc * z + C0;
                h2 relu  = __builtin_elementwise_max(U.hv, HZERO);
                gg.g2[pr] = relu + delta;
            }

            // h += gelu(u) @ (V/N)  (residual add folded into MFMA C operand)
            h[t] = __builtin_amdgcn_mfma_f32_16x16x16f16(vf, gg.h4, h[t], 0, 0, 0);
        }

        wf = wfn; vf = vfn;
    }

    #pragma unroll
    for (int t = 0; t < 4; ++t) {
        float4 v = make_float4(h[t][0], h[t][1], h[t][2], h[t][3]);
        *reinterpret_cast<float4*>(out + (rowbase + t * 16 + r) * DDIM + 4 * q) = v;
    }
}

extern "C" void kernel_launch(void* const* d_in, const int* in_sizes, int n_in,
                              void* d_out, int out_size, void* d_ws, size_t ws_size,
                              hipStream_t stream) {
    const float* x = (const float*)d_in[0];   // [B, 16] fp32
    const float* W = (const float*)d_in[1];   // [64, 16, 16] fp32
    const float* V = (const float*)d_in[2];   // [64, 16, 16] fp32
    float* out = (float*)d_out;

    half4* pw = (half4*)d_ws;                 // 64 steps * 64 lanes * 8B = 32KB
    half4* pv = pw + NSTEPS * 64;             // +32KB (ws_size >= 64KB)

    pack_wv<<<16, 256, 0, stream>>>(W, V, pw, pv);

    int batch = in_sizes[0] / DDIM;           // 2^21
    resnet_mfma_kernel<<<batch / 256, 256, 0, stream>>>(x, pw, pv, out);
}

// Round 11
// 579.120 us; speedup vs baseline: 1.0712x; 1.0712x over previous
//
#include <hip/hip_runtime.h>
#include <math.h>

#define DDIM 16
#define NSTEPS 64

typedef __fp16   fp16x2  __attribute__((ext_vector_type(2)));
typedef _Float16 half4   __attribute__((ext_vector_type(4)));
typedef float    floatx4 __attribute__((ext_vector_type(4)));

union pk2_to_h4 { fp16x2 p2[2]; half4 h4; };

// ---------------------------------------------------------------------------
// Pre-pack W^T / V^T into per-lane MFMA A-operand fragments (f16).
// V fragments are pre-scaled by 1/NSTEPS.
// ---------------------------------------------------------------------------
__global__ __launch_bounds__(256) void pack_wv(const float* __restrict__ W,
                                               const float* __restrict__ V,
                                               half4* __restrict__ pw,
                                               half4* __restrict__ pv)
{
    int t = blockIdx.x * 256 + threadIdx.x;   // 0..4095 = 64 steps * 64 lanes
    int L = t & 63;
    int s = t >> 6;
    int q = L >> 4, r = L & 15;
    const float inv_n = 1.0f / (float)NSTEPS;
    const float* Ws = W + s * DDIM * DDIM;
    const float* Vs = V + s * DDIM * DDIM;
    half4 w, v;
    #pragma unroll
    for (int j = 0; j < 4; ++j) {
        w[j] = (_Float16)Ws[(4 * q + j) * DDIM + r];
        v[j] = (_Float16)(Vs[(4 * q + j) * DDIM + r] * inv_n);
    }
    pw[t] = w;
    pv[t] = v;
}

// ---------------------------------------------------------------------------
// Main kernel — LDS-free, pure-f32 scalar GELU:
//   gelu(x) = x * (0.5 + xc * A(xc*xc)),  xc = clamp(x, -3.2, 3.2)
// where A(s) = (Phi(sqrt(s)) - 1/2)/sqrt(s), deg-5 polynomial fit on
// s in [0, 10.24] (Newton divided differences on exact normal-CDF nodes;
// |A err| <= ~1.3e-4 -> |gelu err| <= ~1.3e-3; clamp gives the tails free:
// x>3.2 -> g~x, x<-3.2 -> g~0, tail err <= 7e-4*|x|).
// 10 full-rate f32 ops per element (max,min,mul,5 fma,fma,mul) — no LDS,
// no transcendentals, no f16-vector builtins (R9's codegen trap), ~9-deep
// chain. Removes the 4 gathers/tile whose pipe+latency cost was the
// invariant 446-474us floor of R4-R8.
// ---------------------------------------------------------------------------
__global__ __launch_bounds__(256) void resnet_mfma_kernel(
    const float* __restrict__ x,
    const half4* __restrict__ pw,
    const half4* __restrict__ pv,
    float* __restrict__ out)
{
    const int tid  = threadIdx.x;
    const int lane = tid & 63;
    const int wave = tid >> 6;
    const int q = lane >> 4, r = lane & 15;

    const long rowbase = (long)blockIdx.x * 256 + (long)wave * 64;

    floatx4 h[4];
    #pragma unroll
    for (int t = 0; t < 4; ++t) {
        const float4* p = reinterpret_cast<const float4*>(
            x + (rowbase + t * 16 + r) * DDIM + 4 * q);
        float4 v = *p;
        h[t][0] = v.x; h[t][1] = v.y; h[t][2] = v.z; h[t][3] = v.w;
    }

    // A(s) deg-5 coefficients (power basis), s = xc^2 in [0, 10.24]
    const float C5 = -1.073e-6f;
    const float C4 =  4.59936e-5f;
    const float C3 = -8.5051366e-4f;
    const float C2 =  9.1374625e-3f;
    const float C1 = -0.0656819025f;
    const float C0 =  0.3988126128f;

    half4 wf = pw[lane];
    half4 vf = pv[lane];

    for (int s = 0; s < NSTEPS; ++s) {
        int sn = (s + 1) & (NSTEPS - 1);          // last iter wraps to 0 (unused)
        half4 wfn = pw[sn * 64 + lane];
        half4 vfn = pv[sn * 64 + lane];

        #pragma unroll
        for (int t = 0; t < 4; ++t) {
            pk2_to_h4 hc;
            hc.p2[0] = __builtin_amdgcn_cvt_pkrtz(h[t][0], h[t][1]);
            hc.p2[1] = __builtin_amdgcn_cvt_pkrtz(h[t][2], h[t][3]);

            floatx4 zero = {0.f, 0.f, 0.f, 0.f};
            floatx4 u = __builtin_amdgcn_mfma_f32_16x16x16f16(wf, hc.h4, zero, 0, 0, 0);

            // g = gelu(u), pure f32 scalar ops
            float g0[4];
            #pragma unroll
            for (int j = 0; j < 4; ++j) {
                float xv = u[j];
                float xc = fminf(fmaxf(xv, -3.2f), 3.2f);
                float sq = xc * xc;
                float acc = fmaf(C5, sq, C4);
                acc = fmaf(acc, sq, C3);
                acc = fmaf(acc, sq, C2);
                acc = fmaf(acc, sq, C1);
                acc = fmaf(acc, sq, C0);
                float P = fmaf(xc, acc, 0.5f);    // Phi(xc) approx
                g0[j] = xv * P;
            }

            pk2_to_h4 gc;
            gc.p2[0] = __builtin_amdgcn_cvt_pkrtz(g0[0], g0[1]);
            gc.p2[1] = __builtin_amdgcn_cvt_pkrtz(g0[2], g0[3]);

            // h += gelu(u) @ (V/N)  (residual add folded into MFMA C operand)
            h[t] = __builtin_amdgcn_mfma_f32_16x16x16f16(vf, gc.h4, h[t], 0, 0, 0);
        }

        wf = wfn; vf = vfn;
    }

    #pragma unroll
    for (int t = 0; t < 4; ++t) {
        float4 v = make_float4(h[t][0], h[t][1], h[t][2], h[t][3]);
        *reinterpret_cast<float4*>(out + (rowbase + t * 16 + r) * DDIM + 4 * q) = v;
    }
}

extern "C" void kernel_launch(void* const* d_in, const int* in_sizes, int n_in,
                              void* d_out, int out_size, void* d_ws, size_t ws_size,
                              hipStream_t stream) {
    const float* x = (const float*)d_in[0];   // [B, 16] fp32
    const float* W = (const float*)d_in[1];   // [64, 16, 16] fp32
    const float* V = (const float*)d_in[2];   // [64, 16, 16] fp32
    float* out = (float*)d_out;

    half4* pw = (half4*)d_ws;                 // 64 steps * 64 lanes * 8B = 32KB
    half4* pv = pw + NSTEPS * 64;             // +32KB (ws_size >= 64KB)

    pack_wv<<<16, 256, 0, stream>>>(W, V, pw, pv);

    int batch = in_sizes[0] / DDIM;           // 2^21
    resnet_mfma_kernel<<<batch / 256, 256, 0, stream>>>(x, pw, pv, out);
}

// Round 12
// 403.402 us; speedup vs baseline: 1.5378x; 1.4356x over previous
//
#include <hip/hip_runtime.h>
#include <math.h>

#define DDIM 16
#define NSTEPS 64

typedef __fp16   fp16x2  __attribute__((ext_vector_type(2)));
typedef _Float16 h2      __attribute__((ext_vector_type(2)));
typedef _Float16 half4   __attribute__((ext_vector_type(4)));
typedef float    floatx4 __attribute__((ext_vector_type(4)));

union pk_u      { fp16x2 fv; h2 hv; unsigned u; };
union h2x2_h4   { h2 g2[2]; half4 h4; };
union pk2_to_h4 { fp16x2 p2[2]; half4 h4; };
union us_h      { unsigned short u; _Float16 h; };

// ---------------------------------------------------------------------------
// Pre-pack W^T / V^T into per-lane MFMA A-operand fragments (f16).
// V fragments are pre-scaled by 1/NSTEPS.
// ---------------------------------------------------------------------------
__global__ __launch_bounds__(256) void pack_wv(const float* __restrict__ W,
                                               const float* __restrict__ V,
                                               half4* __restrict__ pw,
                                               half4* __restrict__ pv)
{
    int t = blockIdx.x * 256 + threadIdx.x;   // 0..4095 = 64 steps * 64 lanes
    int L = t & 63;
    int s = t >> 6;
    int q = L >> 4, r = L & 15;
    const float inv_n = 1.0f / (float)NSTEPS;
    const float* Ws = W + s * DDIM * DDIM;
    const float* Vs = V + s * DDIM * DDIM;
    half4 w, v;
    #pragma unroll
    for (int j = 0; j < 4; ++j) {
        w[j] = (_Float16)Ws[(4 * q + j) * DDIM + r];
        v[j] = (_Float16)(Vs[(4 * q + j) * DDIM + r] * inv_n);
    }
    pw[t] = w;
    pv[t] = v;
}

// ---------------------------------------------------------------------------
// GELU LUT indexed by the TOP 10 BITS of the f16 pattern of x
// (sign + 5 exp + 4 mantissa): 1024 log-spaced segments covering the whole
// f16 domain -> no clamping needed. Entry i: packed f16 (a,b), low16=a,
// with gelu(x) ~= a*x + b on the segment [bits(i<<6), bits((i+1)<<6)).
// Segments touching inf/nan encodings: g=x (positive) or g=0 (negative) —
// exact there. Max PWL error ~6e-4 (binade [1,2)), below f16 activation ulp.
// ---------------------------------------------------------------------------
__global__ __launch_bounds__(256) void build_lut16(unsigned* __restrict__ lut)
{
    int i = blockIdx.x * 256 + threadIdx.x;   // 0..1023
    int sign = i >> 9;
    int eo = (i >> 4) & 31;
    int en = ((i + 1) >> 4) & 31;
    float a, b;
    if (eo == 31 || en == 31) {               // segment touches inf/nan codes
        a = sign ? 0.0f : 1.0f;
        b = 0.0f;
    } else {
        us_h c0, c1;
        c0.u = (unsigned short)(i << 6);
        c1.u = (unsigned short)((i + 1) << 6);
        float x0 = (float)c0.h, x1 = (float)c1.h;
        float g0 = 0.5f * x0 * (1.0f + erff(x0 * 0.70710678f));
        float g1 = 0.5f * x1 * (1.0f + erff(x1 * 0.70710678f));
        a = (g1 - g0) / (x1 - x0);
        b = g0 - a * x0;
    }
    us_h ah, bh;
    ah.h = (_Float16)a;
    bh.h = (_Float16)b;
    lut[i] = ((unsigned)bh.u << 16) | (unsigned)ah.u;
}

// ---------------------------------------------------------------------------
// Main kernel (best-measured structure, round-4 source). GELU per tile:
//   2x cvt_pkrtz (u->f16, needed for MFMA operand anyway)
//   4x (lshr+and) byte-offset from the f16 bits
//   4x ds_read_b32 gather (4KB LUT)
//   4x v_perm repack (a|b interleave -> a-pair / b-pair)
//   2x v_pk_fma_f16 -> result IS the f16 MFMA B-operand (no output pkrtz)
// Empirical cost model across R0-R10: cy/tile ~= 2*VALU + ~80 (const is
// invariant to occupancy/conflicts/gather-depth/LDS-presence); this kernel
// minimizes the VALU term — measured 399us bench / 446us dispatch.
// ---------------------------------------------------------------------------
__global__ __launch_bounds__(256) void resnet_mfma_kernel(
    const float* __restrict__ x,
    const half4* __restrict__ pw,
    const half4* __restrict__ pv,
    const unsigned* __restrict__ lut_g,
    float* __restrict__ out)
{
    __shared__ unsigned lutw[1024];   // 4 KB

    const int tid  = threadIdx.x;
    const int lane = tid & 63;
    const int wave = tid >> 6;
    const int q = lane >> 4, r = lane & 15;

    // Stage LUT into LDS: 256 uint4 = 1024 u32, one per thread.
    {
        const uint4* src = reinterpret_cast<const uint4*>(lut_g);
        reinterpret_cast<uint4*>(lutw)[tid] = src[tid];
    }

    const long rowbase = (long)blockIdx.x * 256 + (long)wave * 64;

    floatx4 h[4];
    #pragma unroll
    for (int t = 0; t < 4; ++t) {
        const float4* p = reinterpret_cast<const float4*>(
            x + (rowbase + t * 16 + r) * DDIM + 4 * q);
        float4 v = *p;
        h[t][0] = v.x; h[t][1] = v.y; h[t][2] = v.z; h[t][3] = v.w;
    }

    half4 wf = pw[lane];
    half4 vf = pv[lane];

    __syncthreads();   // LUT ready

    const char* lb = reinterpret_cast<const char*>(lutw);

    for (int s = 0; s < NSTEPS; ++s) {
        int sn = (s + 1) & (NSTEPS - 1);          // last iter wraps to 0 (unused)
        half4 wfn = pw[sn * 64 + lane];
        half4 vfn = pv[sn * 64 + lane];

        #pragma unroll
        for (int t = 0; t < 4; ++t) {
            pk2_to_h4 hc;
            hc.p2[0] = __builtin_amdgcn_cvt_pkrtz(h[t][0], h[t][1]);
            hc.p2[1] = __builtin_amdgcn_cvt_pkrtz(h[t][2], h[t][3]);

            floatx4 zero = {0.f, 0.f, 0.f, 0.f};
            floatx4 u = __builtin_amdgcn_mfma_f32_16x16x16f16(wf, hc.h4, zero, 0, 0, 0);

            // u -> packed f16 (also the value fed to the PWL eval)
            pk_u p01, p23;
            p01.fv = __builtin_amdgcn_cvt_pkrtz(u[0], u[1]);
            p23.fv = __builtin_amdgcn_cvt_pkrtz(u[2], u[3]);

            // byte offsets = (f16 bits >> 6) * 4, straight from the packed words
            unsigned off0 = (p01.u >> 4) & 0xFFCu;
            unsigned off1 = (p01.u >> 20) & 0xFFCu;
            unsigned off2 = (p23.u >> 4) & 0xFFCu;
            unsigned off3 = (p23.u >> 20) & 0xFFCu;

            unsigned e0 = *reinterpret_cast<const unsigned*>(lb + off0);
            unsigned e1 = *reinterpret_cast<const unsigned*>(lb + off1);
            unsigned e2 = *reinterpret_cast<const unsigned*>(lb + off2);
            unsigned e3 = *reinterpret_cast<const unsigned*>(lb + off3);

            // repack (b|a)(b|a) -> (a1|a0), (b1|b0) ; then packed f16 fma
            pk_u a01, b01, a23, b23;
            a01.u = __builtin_amdgcn_perm(e1, e0, 0x05040100u);
            b01.u = __builtin_amdgcn_perm(e1, e0, 0x07060302u);
            a23.u = __builtin_amdgcn_perm(e3, e2, 0x05040100u);
            b23.u = __builtin_amdgcn_perm(e3, e2, 0x07060302u);

            h2x2_h4 gg;
            gg.g2[0] = a01.hv * p01.hv + b01.hv;   // v_pk_fma_f16
            gg.g2[1] = a23.hv * p23.hv + b23.hv;

            // h += gelu(u) @ (V/N)  (residual add folded into MFMA C operand)
            h[t] = __builtin_amdgcn_mfma_f32_16x16x16f16(vf, gg.h4, h[t], 0, 0, 0);
        }

        wf = wfn; vf = vfn;
    }

    #pragma unroll
    for (int t = 0; t < 4; ++t) {
        float4 v = make_float4(h[t][0], h[t][1], h[t][2], h[t][3]);
        *reinterpret_cast<float4*>(out + (rowbase + t * 16 + r) * DDIM + 4 * q) = v;
    }
}

extern "C" void kernel_launch(void* const* d_in, const int* in_sizes, int n_in,
                              void* d_out, int out_size, void* d_ws, size_t ws_size,
                              hipStream_t stream) {
    const float* x = (const float*)d_in[0];   // [B, 16] fp32
    const float* W = (const float*)d_in[1];   // [64, 16, 16] fp32
    const float* V = (const float*)d_in[2];   // [64, 16, 16] fp32
    float* out = (float*)d_out;

    half4* pw = (half4*)d_ws;                 // 64 steps * 64 lanes * 8B = 32KB
    half4* pv = pw + NSTEPS * 64;             // +32KB
    unsigned* lut = (unsigned*)(pv + NSTEPS * 64); // +4KB (ws_size >= 68KB)

    pack_wv<<<16, 256, 0, stream>>>(W, V, pw, pv);
    build_lut16<<<4, 256, 0, stream>>>(lut);

    int batch = in_sizes[0] / DDIM;           // 2^21
    resnet_mfma_kernel<<<batch / 256, 256, 0, stream>>>(x, pw, pv, lut, out);
}

// Round 14
// 400.945 us; speedup vs baseline: 1.5472x; 1.0061x over previous
//
#include <hip/hip_runtime.h>
#include <math.h>

#define DDIM 16
#define NSTEPS 64

typedef __fp16   fp16x2  __attribute__((ext_vector_type(2)));
typedef _Float16 h2      __attribute__((ext_vector_type(2)));
typedef _Float16 half4   __attribute__((ext_vector_type(4)));
typedef float    floatx4 __attribute__((ext_vector_type(4)));

union pk_u      { fp16x2 fv; h2 hv; unsigned u; };
union h2x2_h4   { h2 g2[2]; half4 h4; };
union pk2_to_h4 { fp16x2 p2[2]; half4 h4; };
union us_h      { unsigned short u; _Float16 h; };

// ---------------------------------------------------------------------------
// Pre-pack W^T / V^T into per-lane MFMA A-operand fragments (f16).
// V fragments are pre-scaled by 1/NSTEPS.
// ---------------------------------------------------------------------------
__global__ __launch_bounds__(256) void pack_wv(const float* __restrict__ W,
                                               const float* __restrict__ V,
                                               half4* __restrict__ pw,
                                               half4* __restrict__ pv)
{
    int t = blockIdx.x * 256 + threadIdx.x;   // 0..4095 = 64 steps * 64 lanes
    int L = t & 63;
    int s = t >> 6;
    int q = L >> 4, r = L & 15;
    const float inv_n = 1.0f / (float)NSTEPS;
    const float* Ws = W + s * DDIM * DDIM;
    const float* Vs = V + s * DDIM * DDIM;
    half4 w, v;
    #pragma unroll
    for (int j = 0; j < 4; ++j) {
        w[j] = (_Float16)Ws[(4 * q + j) * DDIM + r];
        v[j] = (_Float16)(Vs[(4 * q + j) * DDIM + r] * inv_n);
    }
    pw[t] = w;
    pv[t] = v;
}

// ---------------------------------------------------------------------------
// GELU LUT indexed by the TOP 10 BITS of the f16 pattern of x
// (sign + 5 exp + 4 mantissa): 1024 log-spaced segments covering the whole
// f16 domain -> no clamping needed. Entry i: packed f16 (a,b), low16=a,
// with gelu(x) ~= a*x + b on the segment [bits(i<<6), bits((i+1)<<6)).
// Segments touching inf/nan encodings: g=x (positive) or g=0 (negative) —
// exact there. Max PWL error ~6e-4 (binade [1,2)), below f16 activation ulp.
// ---------------------------------------------------------------------------
__global__ __launch_bounds__(256) void build_lut16(unsigned* __restrict__ lut)
{
    int i = blockIdx.x * 256 + threadIdx.x;   // 0..1023
    int sign = i >> 9;
    int eo = (i >> 4) & 31;
    int en = ((i + 1) >> 4) & 31;
    float a, b;
    if (eo == 31 || en == 31) {               // segment touches inf/nan codes
        a = sign ? 0.0f : 1.0f;
        b = 0.0f;
    } else {
        us_h c0, c1;
        c0.u = (unsigned short)(i << 6);
        c1.u = (unsigned short)((i + 1) << 6);
        float x0 = (float)c0.h, x1 = (float)c1.h;
        float g0 = 0.5f * x0 * (1.0f + erff(x0 * 0.70710678f));
        float g1 = 0.5f * x1 * (1.0f + erff(x1 * 0.70710678f));
        a = (g1 - g0) / (x1 - x0);
        b = g0 - a * x0;
    }
    us_h ah, bh;
    ah.h = (_Float16)a;
    bh.h = (_Float16)b;
    lut[i] = ((unsigned)bh.u << 16) | (unsigned)ah.u;
}

// ---------------------------------------------------------------------------
// Main kernel (best-measured structure; benched 399-403us twice). GELU/tile:
//   2x cvt_pkrtz (u->f16, needed for MFMA operand anyway)
//   4x (lshr+and) byte-offset from the f16 bits
//   4x ds_read_b32 gather (4KB LUT)
//   4x v_perm repack (a|b interleave -> a-pair / b-pair)
//   2x v_pk_fma_f16 -> result IS the f16 MFMA B-operand (no output pkrtz)
// Cost law fitted over R0-R10: cy/tile ~= 2*VALU + ~80 (constant invariant
// to occupancy/conflicts/gather-depth/LDS-presence). This kernel minimizes
// the VALU term; modeled remaining headroom of the structure <= ~5%.
// R12's op_sel v_fma_f16 variant (-4 VALU) MISCOMPUTES on gfx950 (src2
// op_sel / dest-half-preserve not honored) — do not retry without an
// ISA-level unit test.
// ---------------------------------------------------------------------------
__global__ __launch_bounds__(256) void resnet_mfma_kernel(
    const float* __restrict__ x,
    const half4* __restrict__ pw,
    const half4* __restrict__ pv,
    const unsigned* __restrict__ lut_g,
    float* __restrict__ out)
{
    __shared__ unsigned lutw[1024];   // 4 KB

    const int tid  = threadIdx.x;
    const int lane = tid & 63;
    const int wave = tid >> 6;
    const int q = lane >> 4, r = lane & 15;

    // Stage LUT into LDS: 256 uint4 = 1024 u32, one per thread.
    {
        const uint4* src = reinterpret_cast<const uint4*>(lut_g);
        reinterpret_cast<uint4*>(lutw)[tid] = src[tid];
    }

    const long rowbase = (long)blockIdx.x * 256 + (long)wave * 64;

    floatx4 h[4];
    #pragma unroll
    for (int t = 0; t < 4; ++t) {
        const float4* p = reinterpret_cast<const float4*>(
            x + (rowbase + t * 16 + r) * DDIM + 4 * q);
        float4 v = *p;
        h[t][0] = v.x; h[t][1] = v.y; h[t][2] = v.z; h[t][3] = v.w;
    }

    half4 wf = pw[lane];
    half4 vf = pv[lane];

    __syncthreads();   // LUT ready

    const char* lb = reinterpret_cast<const char*>(lutw);

    for (int s = 0; s < NSTEPS; ++s) {
        int sn = (s + 1) & (NSTEPS - 1);          // last iter wraps to 0 (unused)
        half4 wfn = pw[sn * 64 + lane];
        half4 vfn = pv[sn * 64 + lane];

        #pragma unroll
        for (int t = 0; t < 4; ++t) {
            pk2_to_h4 hc;
            hc.p2[0] = __builtin_amdgcn_cvt_pkrtz(h[t][0], h[t][1]);
            hc.p2[1] = __builtin_amdgcn_cvt_pkrtz(h[t][2], h[t][3]);

            floatx4 zero = {0.f, 0.f, 0.f, 0.f};
            floatx4 u = __builtin_amdgcn_mfma_f32_16x16x16f16(wf, hc.h4, zero, 0, 0, 0);

            // u -> packed f16 (also the value fed to the PWL eval)
            pk_u p01, p23;
            p01.fv = __builtin_amdgcn_cvt_pkrtz(u[0], u[1]);
            p23.fv = __builtin_amdgcn_cvt_pkrtz(u[2], u[3]);

            // byte offsets = (f16 bits >> 6) * 4, straight from the packed words
            unsigned off0 = (p01.u >> 4) & 0xFFCu;
            unsigned off1 = (p01.u >> 20) & 0xFFCu;
            unsigned off2 = (p23.u >> 4) & 0xFFCu;
            unsigned off3 = (p23.u >> 20) & 0xFFCu;

            unsigned e0 = *reinterpret_cast<const unsigned*>(lb + off0);
            unsigned e1 = *reinterpret_cast<const unsigned*>(lb + off1);
            unsigned e2 = *reinterpret_cast<const unsigned*>(lb + off2);
            unsigned e3 = *reinterpret_cast<const unsigned*>(lb + off3);

            // repack (b|a)(b|a) -> (a1|a0), (b1|b0) ; then packed f16 fma
            pk_u a01, b01, a23, b23;
            a01.u = __builtin_amdgcn_perm(e1, e0, 0x05040100u);
            b01.u = __builtin_amdgcn_perm(e1, e0, 0x07060302u);
            a23.u = __builtin_amdgcn_perm(e3, e2, 0x05040100u);
            b23.u = __builtin_amdgcn_perm(e3, e2, 0x07060302u);

            h2x2_h4 gg;
            gg.g2[0] = a01.hv * p01.hv + b01.hv;   // v_pk_fma_f16
            gg.g2[1] = a23.hv * p23.hv + b23.hv;

            // h += gelu(u) @ (V/N)  (residual add folded into MFMA C operand)
            h[t] = __builtin_amdgcn_mfma_f32_16x16x16f16(vf, gg.h4, h[t], 0, 0, 0);
        }

        wf = wfn; vf = vfn;
    }

    #pragma unroll
    for (int t = 0; t < 4; ++t) {
        float4 v = make_float4(h[t][0], h[t][1], h[t][2], h[t][3]);
        *reinterpret_cast<float4*>(out + (rowbase + t * 16 + r) * DDIM + 4 * q) = v;
    }
}

extern "C" void kernel_launch(void* const* d_in, const int* in_sizes, int n_in,
                              void* d_out, int out_size, void* d_ws, size_t ws_size,
                              hipStream_t stream) {
    const float* x = (const float*)d_in[0];   // [B, 16] fp32
    const float* W = (const float*)d_in[1];   // [64, 16, 16] fp32
    const float* V = (const float*)d_in[2];   // [64, 16, 16] fp32
    float* out = (float*)d_out;

    half4* pw = (half4*)d_ws;                 // 64 steps * 64 lanes * 8B = 32KB
    half4* pv = pw + NSTEPS * 64;             // +32KB
    unsigned* lut = (unsigned*)(pv + NSTEPS * 64); // +4KB (ws_size >= 68KB)

    pack_wv<<<16, 256, 0, stream>>>(W, V, pw, pv);
    build_lut16<<<4, 256, 0, stream>>>(lut);

    int batch = in_sizes[0] / DDIM;           // 2^21
    resnet_mfma_kernel<<<batch / 256, 256, 0, stream>>>(x, pw, pv, lut, out);
}